// Round 1
// baseline (777.422 us; speedup 1.0000x reference)
//
#include <hip/hip_runtime.h>

#define ENTITIES_N 100000
#define RELATIONS_N 1000
#define WIDTH (2 * ENTITIES_N + RELATIONS_N)   // 201000
#define BATCH_MAX 1024

// One thread per batch row: write the three 1.0s for that row.
// h-col in [0, E), r-col in [E, E+R), t-col in [E+R, 2E+R) -- disjoint, no conflicts.
__global__ void scatter_ones_i32(const int* __restrict__ hID,
                                 const int* __restrict__ rID,
                                 const int* __restrict__ tID,
                                 float* __restrict__ out, int batch) {
    int row = blockIdx.x * blockDim.x + threadIdx.x;
    if (row >= batch) return;
    long long base = (long long)row * WIDTH;
    out[base + (long long)hID[row]] = 1.0f;
    out[base + ENTITIES_N + (long long)rID[row]] = 1.0f;
    out[base + ENTITIES_N + RELATIONS_N + (long long)tID[row]] = 1.0f;
}

__global__ void scatter_ones_i64(const long long* __restrict__ hID,
                                 const int* __restrict__ rID,
                                 const int* __restrict__ tID,
                                 float* __restrict__ out, int batch) {
    int row = blockIdx.x * blockDim.x + threadIdx.x;
    if (row >= batch) return;
    long long base = (long long)row * WIDTH;
    out[base + hID[row]] = 1.0f;
    out[base + ENTITIES_N + (long long)rID[row]] = 1.0f;
    out[base + ENTITIES_N + RELATIONS_N + (long long)tID[row]] = 1.0f;
}

extern "C" void kernel_launch(void* const* d_in, const int* in_sizes, int n_in,
                              void* d_out, int out_size, void* d_ws, size_t ws_size,
                              hipStream_t stream) {
    // Inputs (setup_inputs order): z [B,128] f32 (unused), hID [B] int, rID [B] i32, tID [B] i32
    const int* rID = (const int*)d_in[2];
    const int* tID = (const int*)d_in[3];
    float* out = (float*)d_out;

    const int batch = in_sizes[2];  // rID is definitely int32, one elem per row

    // Zero the whole output (harness poisons it to 0xAA before every launch).
    // hipMemsetAsync is graph-capturable and hits near-peak write BW.
    hipMemsetAsync(d_out, 0, (size_t)out_size * sizeof(float), stream);

    const int block = 256;
    const int grid = (batch + block - 1) / block;
    if (in_sizes[1] == batch) {
        // hID delivered as int32
        scatter_ones_i32<<<grid, block, 0, stream>>>((const int*)d_in[1], rID, tID, out, batch);
    } else {
        // hID delivered as int64 (element count would differ)
        scatter_ones_i64<<<grid, block, 0, stream>>>((const long long*)d_in[1], rID, tID, out, batch);
    }
}